// Round 1
// 4919.222 us; speedup vs baseline: 1.1271x; 1.1271x over previous
//
#include <hip/hip_runtime.h>
#include <math.h>

#define TPB 1024
#define NBLK 256
#define NBATCH 32
#define NT 64
#define NH 512
#define NM 128
#define NR 4
#define NW 64
#define NI 768          // controller input size (H + R*W)
#define NXI 471         // interface vector size
#define NG 2048         // gate rows
#define EPSF 1e-6f
#define MS 65           // mem row stride (+1 pad)

// roles: [0,32) state | [32,160) gates(128) | [160,190) xi(30) | [192,256) out(64)

typedef float f4 __attribute__((ext_vector_type(4)));

// ws layout (float offsets). pub* parity double-buffered.
#define WS_LINK  0                                 // [32][128*128]
#define WS_PUBH  (WS_LINK + NBATCH*NM*NM)          // [2][32][512]
#define WS_PUBRV (WS_PUBH + 2*NBATCH*NH)           // [2][32][256]
#define WS_PUBG  (WS_PUBRV + 2*NBATCH*NR*NW)       // [2][32][2048]
#define WS_PUBXI (WS_PUBG + 2*NBATCH*NG)           // [2][32][480]
#define WS_FLAGS (WS_PUBXI + 2*NBATCH*480)         // per-producer flag lines
// flag arrays (uint offsets inside flag region); each flag on its own 64B line
#define F_H 0        // 32 state blocks: h published (init=1, after h(t): t+2)
#define F_R 512      // 32 state blocks: rv published (same encoding)
#define F_G 1024     // 128 gates blocks: gates(t) -> t+1
#define F_X 3072     // 30 xi blocks: xi(t) -> t+1
#define F_O 3584     // 64 out blocks: out(t) -> t+1
#define F_TOTAL 4608

__device__ __forceinline__ float sigm(float x){ return 1.0f/(1.0f+expf(-x)); }
__device__ __forceinline__ float sftp(float x){ return fmaxf(x,0.0f)+log1pf(expf(-fabsf(x))); }
__device__ __forceinline__ float dot4(f4 a, f4 b){
    return a.x*b.x + a.y*b.y + a.z*b.z + a.w*b.w;
}
__device__ __forceinline__ float wave_red(float v){
    #pragma unroll
    for (int o = 32; o > 0; o >>= 1) v += __shfl_down(v, o);
    return v;
}

// ---- coherent (L1/L2-bypassing, device-visible) WIDE accessors: sc0 sc1 ----
// waitcnt lives INSIDE each asm statement => value is genuinely ready when the
// statement retires (no rule-18 hoist hazard). Outputs early-clobber.
__device__ __forceinline__ f4 cload4(const float* p){
    f4 v;
    asm volatile("global_load_dwordx4 %0, %1, off sc0 sc1\n\t"
                 "s_waitcnt vmcnt(0)"
                 : "=&v"(v) : "v"(p) : "memory");
    return v;
}
__device__ __forceinline__ void cload4x2(const float* p0, const float* p1,
                                         f4& a, f4& b){
    asm volatile("global_load_dwordx4 %0, %2, off sc0 sc1\n\t"
                 "global_load_dwordx4 %1, %3, off sc0 sc1\n\t"
                 "s_waitcnt vmcnt(0)"
                 : "=&v"(a), "=&v"(b) : "v"(p0), "v"(p1) : "memory");
}
__device__ __forceinline__ void cload1x4(const float* p0, const float* p1,
                                         const float* p2, const float* p3,
                                         float& a, float& b, float& c, float& d){
    asm volatile("global_load_dword %0, %4, off sc0 sc1\n\t"
                 "global_load_dword %1, %5, off sc0 sc1\n\t"
                 "global_load_dword %2, %6, off sc0 sc1\n\t"
                 "global_load_dword %3, %7, off sc0 sc1\n\t"
                 "s_waitcnt vmcnt(0)"
                 : "=&v"(a), "=&v"(b), "=&v"(c), "=&v"(d)
                 : "v"(p0), "v"(p1), "v"(p2), "v"(p3) : "memory");
}
__device__ __forceinline__ void cstore4(float* p, f4 v){
    asm volatile("global_store_dwordx4 %0, %1, off sc0 sc1"
                 :: "v"(p), "v"(v) : "memory");
}

// ---- per-producer flag protocol: parallel polls, no RMW contention ----
__device__ __forceinline__ void multi_wait(const unsigned int* f, int n,
                                           unsigned int tgt, int tid){
    if (tid < n) {
        const unsigned int* p = f + tid*16;       // one 64B line per flag
        while (__hip_atomic_load(p, __ATOMIC_RELAXED,
                                 __HIP_MEMORY_SCOPE_AGENT) < tgt)
            __builtin_amdgcn_s_sleep(2);
    }
    __syncthreads();
}
__device__ __forceinline__ void flag_set(unsigned int* f, unsigned int v, int tid){
    // every wave drains its own (asm) stores, then barrier, then one release store
    asm volatile("s_waitcnt vmcnt(0)" ::: "memory");
    __syncthreads();
    if (tid == 0)
        __hip_atomic_store(f, v, __ATOMIC_RELEASE, __HIP_MEMORY_SCOPE_AGENT);
}

__global__ void dnc_zero(float* ws){
    unsigned int* z = (unsigned int*)(ws + WS_FLAGS);
    for (int e = threadIdx.x; e < F_TOTAL; e += blockDim.x) z[e] = 0u;
}

// ---- pooled LDS (floats) ----
#define O_MEM 0
#define O_H   8320
#define O_C   8832
#define O_RW  9344
#define O_WWO 9856
#define O_WWN 9984
#define O_USG 10112
#define O_PRC 10240
#define O_XI  10368     // 480 (padded for f4 loads)
#define O_KEY 10848
#define O_WK  11104
#define O_ER  11168
#define O_WV  11232
#define O_RS  11296
#define O_FG  11300
#define O_MD  11304
#define O_NK  11316
#define O_SC  11320
#define O_NMO 11328
#define O_NMN 11456
#define O_WCW 11584
#define O_UU  11712
#define O_SU  11840
#define O_CUM 11968
#define O_RNK 12096
#define O_CCW 12224
#define O_FWD 12736
#define O_RV  13248
#define O_RED 13504
#define S_SZ  13512
// gates/xi role: staging S[0..8191], acc at 8192..8703 (disjoint role, safe)
#define O_ACC 8192

__global__ __launch_bounds__(TPB) void dnc_pipe2(
    const float* __restrict__ x, const float* __restrict__ W_ih,
    const float* __restrict__ W_hh, const float* __restrict__ b_ih,
    const float* __restrict__ b_hh, const float* __restrict__ W_xi,
    const float* __restrict__ b_xi, const float* __restrict__ W_o,
    const float* __restrict__ b_o, float* __restrict__ out,
    float* __restrict__ ws)
{
    __shared__ __align__(16) float S[S_SZ];

    const int tid = threadIdx.x;
    const int wv  = tid >> 6;
    const int l   = tid & 63;
    const int bid = blockIdx.x;

    float* __restrict__ pubH  = ws + WS_PUBH;
    float* __restrict__ pubRV = ws + WS_PUBRV;
    float* __restrict__ pubG  = ws + WS_PUBG;
    float* __restrict__ pubXI = ws + WS_PUBXI;
    unsigned int* __restrict__ FLG = (unsigned int*)(ws + WS_FLAGS);

    if (bid < NBATCH) {
        // ========================= STATE block =========================
        const int b = bid;
        float* __restrict__ lk = ws + WS_LINK + (size_t)b*NM*NM;
        float* mem = S+O_MEM;  float* hS = S+O_H;   float* cS = S+O_C;
        float* rwS = S+O_RW;   float* wwO = S+O_WWO; float* wwN = S+O_WWN;
        float* usg = S+O_USG;  float* prc = S+O_PRC; float* xiS = S+O_XI;
        float* keys = S+O_KEY; float* wkey = S+O_WK; float* ers = S+O_ER;
        float* wvec = S+O_WV;  float* rstr = S+O_RS; float* fgte = S+O_FG;
        float* modes = S+O_MD; float* nkey = S+O_NK; float* sc = S+O_SC;
        float* nmo = S+O_NMO;  float* nmn = S+O_NMN; float* wcw = S+O_WCW;
        float* uu = S+O_UU;    float* su = S+O_SU;   float* cum = S+O_CUM;
        int*   rnk = (int*)(S+O_RNK);
        float* ccw = S+O_CCW;  float* fwdT = S+O_FWD; float* rv = S+O_RV;
        float* red = S+O_RED;

        for (int e = tid; e < NM*NM; e += TPB) lk[e] = 0.0f;
        for (int e = tid; e < NM*NW; e += TPB) mem[(e>>6)*MS + (e&63)] = EPSF;
        for (int e = tid; e < NH; e += TPB){ hS[e]=0.0f; cS[e]=0.0f; }
        for (int e = tid; e < NR*NM; e += TPB) rwS[e]=0.0f;
        for (int e = tid; e < NM; e += TPB){ wwO[e]=0.0f; usg[e]=0.0f; prc[e]=0.0f; }
        // publish h_{-1}=0, rv_{-1}=0 into parity 1 (gates step 0 reads parity 1)
        {
            f4 z4 = {0.0f, 0.0f, 0.0f, 0.0f};
            if (tid < 128) cstore4(&pubH[(size_t)1*NBATCH*NH + b*NH + tid*4], z4);
            if (tid < 64)  cstore4(&pubRV[(size_t)1*NBATCH*NR*NW + b*NR*NW + tid*4], z4);
        }
        flag_set(&FLG[F_H + b*16], 1u, tid);
        flag_set(&FLG[F_R + b*16], 1u, tid);

        for (int t = 0; t < NT; ++t) {
            const int par = t & 1;
            // gates(t) ready (all 128 producer flags, polled in parallel)
            multi_wait(&FLG[F_G], 128, (unsigned)(t+1), tid);
            {
                const float* gb = pubG + ((size_t)par*NBATCH + b)*NG;
                if (tid < NH) {
                    float vi, vf, vg, vo;
                    cload1x4(gb+tid, gb+NH+tid, gb+2*NH+tid, gb+3*NH+tid,
                             vi, vf, vg, vo);
                    float c = sigm(vf)*cS[tid] + sigm(vi)*tanhf(vg);
                    cS[tid] = c;
                    hS[tid] = sigm(vo)*tanhf(c);
                }
            }
            __syncthreads();
            // out(t-2) done before overwriting its h/rv parity
            if (t >= 2) multi_wait(&FLG[F_O], 64, (unsigned)(t-1), tid);
            if (tid < 128) cstore4(&pubH[(size_t)par*NBATCH*NH + b*NH + tid*4],
                                   *(const f4*)&hS[tid*4]);
            flag_set(&FLG[F_H + b*16], (unsigned)(t+2), tid);

            // nmo — no xi dependency; overlaps xi compute
            #pragma unroll
            for (int ri = 0; ri < 8; ++ri) {
                int row = wv*8 + ri;
                float v = mem[row*MS + l];
                float s2 = wave_red(v*v);
                if (l == 0) nmo[row] = sqrtf(s2);
            }
            __syncthreads();

            // xi(t) ready
            multi_wait(&FLG[F_X], 30, (unsigned)(t+1), tid);
            if (tid < 120)
                *(f4*)&xiS[tid*4] =
                    cload4(&pubXI[(size_t)par*NBATCH*480 + b*480 + tid*4]);
            __syncthreads();

            // E1: unpack interface
            if (tid < 256)       keys[tid] = tanhf(xiS[tid]);
            else if (tid < 260)  rstr[tid-256] = sftp(xiS[tid]);
            else if (tid < 324)  wkey[tid-260] = tanhf(xiS[tid]);
            else if (tid == 324) sc[0] = sftp(xiS[324]);
            else if (tid < 389)  ers[tid-325] = sigm(xiS[tid]);
            else if (tid < 453)  wvec[tid-389] = tanhf(xiS[tid]);
            else if (tid < 457)  fgte[tid-453] = sigm(xiS[tid]);
            else if (tid == 457) sc[1] = sigm(xiS[457]);
            else if (tid == 458) sc[2] = sigm(xiS[458]);
            else if (tid < 463) {
                int r = tid - 459;
                float a0=xiS[459+3*r], a1=xiS[460+3*r], a2=xiS[461+3*r];
                float mx = fmaxf(a0, fmaxf(a1, a2));
                float e0=expf(a0-mx), e1=expf(a1-mx), e2=expf(a2-mx);
                float si = 1.0f/(e0+e1+e2);
                modes[3*r]=e0*si; modes[3*r+1]=e1*si; modes[3*r+2]=e2*si;
            }
            __syncthreads();

            // E2a: key norms
            if (tid < NR) {
                float ssum = 0.0f;
                for (int w = 0; w < NW; ++w) { float v = keys[tid*NW+w]; ssum += v*v; }
                nkey[tid] = sqrtf(ssum);
            } else if (tid == NR) {
                float ssum = 0.0f;
                for (int w = 0; w < NW; ++w) { float v = wkey[w]; ssum += v*v; }
                sc[3] = sqrtf(ssum);
            }
            // E2b: usage + uu (fused)
            if (tid >= 64 && tid < 64+NM) {
                int m = tid - 64;
                float u = usg[m];
                u = u + (1.0f - u)*wwO[m];
                float psi = 1.0f;
                #pragma unroll
                for (int r = 0; r < NR; ++r) psi *= (1.0f - fgte[r]*rwS[r*NM+m]);
                u *= psi;
                usg[m] = u;
                uu[m] = 5e-6f + (1.0f - 5e-6f)*u;
            }
            __syncthreads();

            // F1: write-content logits
            if (tid < NM) {
                float d = 0.0f;
                for (int w = 0; w < NW; ++w) d += wkey[w]*mem[tid*MS+w];
                wcw[tid] = d/(sc[3]*nmo[tid] + EPSF) * sc[0];
            }
            __syncthreads();
            // F2: softmax over 128
            if (tid < 64) {
                float v = fmaxf(wcw[tid], wcw[tid+64]);
                #pragma unroll
                for (int o = 32; o > 0; o >>= 1) v = fmaxf(v, __shfl_down(v, o));
                if (tid == 0) red[0] = v;
            }
            __syncthreads();
            if (tid < NM) wcw[tid] = expf(wcw[tid] - red[0]);
            __syncthreads();
            if (tid < 64) {
                float v = wave_red(wcw[tid] + wcw[tid+64]);
                if (tid == 0) red[0] = 1.0f/v;
            }
            __syncthreads();
            if (tid < NM) wcw[tid] *= red[0];
            __syncthreads();

            // G2: stable rank
            if (tid < NM) {
                float um = uu[tid]; int rk = 0;
                for (int j = 0; j < NM; ++j) {
                    float uj = uu[j];
                    rk += (uj < um) || (uj == um && j < tid);
                }
                rnk[tid] = rk;
                su[rk] = um;
            }
            __syncthreads();
            // G3: product scan (wave 0)
            if (tid < 64) {
                float a = su[tid], bb = su[64+tid];
                #pragma unroll
                for (int o = 1; o < 64; o <<= 1) {
                    float ta = __shfl_up(a, o);
                    float tb = __shfl_up(bb, o);
                    if (tid >= o) { a *= ta; bb *= tb; }
                }
                float P0 = __shfl(a, 63);
                cum[tid] = a;
                cum[64+tid] = P0*bb;
            }
            __syncthreads();
            // G4: alloc + write weighting
            if (tid < NM) {
                int rk = rnk[tid];
                float excl = (rk == 0) ? 1.0f : cum[rk-1];
                float al = (1.0f - uu[tid])*excl;
                wwN[tid] = sc[2]*(sc[1]*al + (1.0f - sc[1])*wcw[tid]);
            }
            __syncthreads();
            // G5: sum(wwN)
            if (tid < 64) {
                float v = wave_red(wwN[tid] + wwN[tid+64]);
                if (tid == 0) sc[4] = v;
            }
            __syncthreads();

            // H (fused): mem erase/write + new norms + link
            #pragma unroll
            for (int ri = 0; ri < 8; ++ri) {
                int row = wv*8 + ri;
                float wm = wwN[row];
                float v = mem[row*MS + l];
                float nv = v*(1.0f - wm*ers[l]) + wm*wvec[l];
                mem[row*MS + l] = nv;
                float s2 = wave_red(nv*nv);
                if (l == 0) nmn[row] = sqrtf(s2);
            }
            for (int e = tid; e < NM*NM; e += TPB) {
                int i = e >> 7, j = e & 127;
                float nl = (i == j) ? 0.0f
                         : (1.0f - wwN[i] - wwN[j])*lk[e] + wwN[i]*prc[j];
                lk[e] = nl;
            }
            __syncthreads();
            // H3: precedence
            if (tid < NM) prc[tid] = (1.0f - sc[4])*prc[tid] + wwN[tid];
            __syncthreads();

            // I: read-content logits + per-r softmax
            if (tid < NR*NM) {
                int r = tid >> 7, m = tid & 127;
                float d = 0.0f;
                for (int w = 0; w < NW; ++w) d += keys[r*NW+w]*mem[m*MS+w];
                ccw[tid] = d/(nkey[r]*nmn[m] + EPSF) * rstr[r];
            }
            __syncthreads();
            if (tid < 256) {
                int r = tid >> 6, ll = tid & 63;
                float v = fmaxf(ccw[r*NM+ll], ccw[r*NM+ll+64]);
                #pragma unroll
                for (int o = 32; o > 0; o >>= 1) v = fmaxf(v, __shfl_down(v, o));
                if (ll == 0) red[r] = v;
            }
            __syncthreads();
            if (tid < NR*NM) ccw[tid] = expf(ccw[tid] - red[tid>>7]);
            __syncthreads();
            if (tid < 256) {
                int r = tid >> 6, ll = tid & 63;
                float v = wave_red(ccw[r*NM+ll] + ccw[r*NM+ll+64]);
                if (ll == 0) red[4+r] = 1.0f/v;
            }
            __syncthreads();
            if (tid < NR*NM) ccw[tid] *= red[4+(tid>>7)];
            __syncthreads();

            // J1: fwd[r][m]
            {
                const int p0 = wv*32;
                for (int i = 0; i < 32; ++i) {
                    const int p = p0 + i, r = p >> 7, m = p & 127;
                    float partial = lk[m*NM + l]*rwS[r*NM + l]
                                  + lk[m*NM + 64 + l]*rwS[r*NM + 64 + l];
                    partial = wave_red(partial);
                    if (l == 0) fwdT[p] = partial;
                }
            }
            __syncthreads();
            // J2: bwd + mode mix
            float rwnew = 0.0f;
            if (tid < NR*NM) {
                int r = tid >> 7, m = tid & 127;
                float bw = 0.0f;
                for (int i = 0; i < NM; ++i) bw += lk[i*NM+m]*rwS[r*NM+i];
                rwnew = modes[3*r]*bw + modes[3*r+1]*fwdT[tid] + modes[3*r+2]*ccw[tid];
            }
            __syncthreads();
            if (tid < NR*NM) rwS[tid] = rwnew;
            __syncthreads();

            // K: read vectors + publish rv (coalesced f4)
            if (tid < NR*NW) {
                int r = tid >> 6, w = tid & 63;
                float ssum = 0.0f;
                for (int m = 0; m < NM; ++m) ssum += rwS[r*NM+m]*mem[m*MS+w];
                rv[tid] = ssum;
            }
            __syncthreads();
            if (tid < 64)
                cstore4(&pubRV[(size_t)par*NBATCH*NR*NW + b*NR*NW + tid*4],
                        *(const f4*)&rv[tid*4]);
            flag_set(&FLG[F_R + b*16], (unsigned)(t+2), tid);

            if (tid < NM) wwO[tid] = wwN[tid];
            __syncthreads();
        }
    } else if (bid < 32 + 128) {
        // ========================= GATES block (16 rows) ====================
        const int g = bid - 32;
        const int r = g*16 + wv;
        const f4* WA = (const f4*)(W_ih + (size_t)r*NI);
        f4 wx0 = WA[l], wx1 = WA[l+64], wrv = WA[128+l];
        const f4* WB = (const f4*)(W_hh + (size_t)r*NH);
        f4 wh0 = WB[l], wh1 = WB[l+64];
        const float bias = b_ih[r] + b_hh[r];
        float* accS = S + O_ACC;   // [32 batches][16 rows] transpose staging
        const int sbi = tid >> 7, sk4 = (tid & 127) << 2;

        for (int t = 0; t < NT; ++t) {
            const int par = t & 1, parp = (t+1) & 1;   // parp = parity of t-1
            // EARLY: x(t) + h(t-1) — overlaps state machinery of step t-1
            multi_wait(&FLG[F_H], 32, (unsigned)(t+1), tid);
            const float* hIn = pubH + (size_t)parp*NBATCH*NH;
            for (int p = 0; p < 4; ++p) {
                const int b0 = p*8;
                // x: 8 batches x 512 (plain cached f4), h: coherent f4
                *(f4*)&S[sbi*512 + sk4] =
                    *(const f4*)&x[((size_t)(b0+sbi)*NT + t)*NH + sk4];
                *(f4*)&S[4096 + sbi*512 + sk4] =
                    cload4(&hIn[(size_t)(b0+sbi)*NH + sk4]);
                __syncthreads();
                #pragma unroll
                for (int bi = 0; bi < 8; ++bi) {
                    const f4* X4 = (const f4*)(S + bi*512);
                    const f4* H4 = (const f4*)(S + 4096 + bi*512);
                    float a = dot4(wx0, X4[l]) + dot4(wx1, X4[l+64])
                            + dot4(wh0, H4[l]) + dot4(wh1, H4[l+64]);
                    a = wave_red(a);
                    if (l == 0) accS[(b0+bi)*16 + wv] = a + bias;
                }
                __syncthreads();
            }
            // LATE: rv(t-1) — the only critical-path part
            multi_wait(&FLG[F_R], 32, (unsigned)(t+1), tid);
            const float* rIn = pubRV + (size_t)parp*NBATCH*NR*NW;
            {
                const int bi0 = tid >> 6, k40 = (tid & 63) << 2;
                f4 a0, a1;
                cload4x2(&rIn[bi0*256 + k40], &rIn[(bi0+16)*256 + k40], a0, a1);
                *(f4*)&S[bi0*256 + k40] = a0;
                *(f4*)&S[(bi0+16)*256 + k40] = a1;
            }
            __syncthreads();
            #pragma unroll
            for (int bi = 0; bi < 32; ++bi) {
                const f4* RV4 = (const f4*)(S + bi*256);
                float d = dot4(wrv, RV4[l]);
                d = wave_red(d);
                if (l == 0) accS[bi*16 + wv] += d;
            }
            __syncthreads();
            // coalesced publish: 16 rows x 4B = one aligned 64B line per batch
            float* gOut = pubG + (size_t)par*NBATCH*NG;
            if (tid < 128) {
                const int bi = tid >> 2, r4 = (tid & 3) << 2;
                cstore4(&gOut[(size_t)bi*NG + g*16 + r4],
                        *(const f4*)&accS[bi*16 + r4]);
            }
            flag_set(&FLG[F_G + g*16], (unsigned)(t+1), tid);
        }
    } else if (bid < 32 + 128 + 32) {
        // ========================= XI block (16 rows) =======================
        const int xg = bid - 160;
        if (xg >= 30) return;          // 30 blocks cover rows 0..479 (pad >470)
        const int row = xg*16 + wv;
        const bool act = row < NXI;
        f4 xa0 = {0,0,0,0}, xa1 = {0,0,0,0}; float bias = 0.0f;
        if (act) {
            const f4* WX = (const f4*)(W_xi + (size_t)row*NH);
            xa0 = WX[l]; xa1 = WX[l+64]; bias = b_xi[row];
        }
        float* accX = S + O_ACC;
        const int sbi = tid >> 7, sk4 = (tid & 127) << 2;
        for (int t = 0; t < NT; ++t) {
            const int par = t & 1;
            multi_wait(&FLG[F_H], 32, (unsigned)(t+2), tid);   // h(t)
            const float* hIn = pubH + (size_t)par*NBATCH*NH;
            float* xOut = pubXI + (size_t)par*NBATCH*480;
            for (int p = 0; p < 4; ++p) {
                const int b0 = p*8;
                *(f4*)&S[sbi*512 + sk4] =
                    cload4(&hIn[(size_t)(b0+sbi)*NH + sk4]);
                __syncthreads();
                #pragma unroll
                for (int bi = 0; bi < 8; ++bi) {
                    const f4* H4 = (const f4*)(S + bi*512);
                    float a = dot4(xa0, H4[l]) + dot4(xa1, H4[l+64]);
                    a = wave_red(a);
                    if (l == 0) accX[(b0+bi)*16 + wv] = a + bias; // pad rows: 0
                }
                __syncthreads();
            }
            // coalesced publish: 16 rows = one aligned 64B chunk per batch
            if (tid < 128) {
                const int bi = tid >> 2, r4 = (tid & 3) << 2;
                cstore4(&xOut[(size_t)bi*480 + xg*16 + r4],
                        *(const f4*)&accX[bi*16 + r4]);
            }
            flag_set(&FLG[F_X + xg*16], (unsigned)(t+1), tid);
        }
    } else {
        // ========================= OUT block (8 rows) =======================
        const int og = bid - 192;
        const int row = og*8 + wv;
        const bool act = (wv < 8);
        f4 o0 = {0,0,0,0}, o1 = {0,0,0,0}, o2 = {0,0,0,0}; float bias = 0.0f;
        if (act) {
            const f4* WO = (const f4*)(W_o + (size_t)row*NI);
            o0 = WO[l]; o1 = WO[l+64]; o2 = WO[128+l]; bias = b_o[row];
        }
        const int hbi = tid >> 7, hk4 = (tid & 127) << 2;
        const int rbi = tid >> 6, rk4 = (tid & 63) << 2;
        for (int t = 0; t < NT; ++t) {
            const int par = t & 1;
            multi_wait(&FLG[F_H], 32, (unsigned)(t+2), tid);   // h(t)
            multi_wait(&FLG[F_R], 32, (unsigned)(t+2), tid);   // rv(t)
            const float* hIn = pubH + (size_t)par*NBATCH*NH;
            const float* rIn = pubRV + (size_t)par*NBATCH*NR*NW;
            for (int p = 0; p < 4; ++p) {
                const int b0 = p*8;
                *(f4*)&S[hbi*768 + hk4] =
                    cload4(&hIn[(size_t)(b0+hbi)*NH + hk4]);
                if (tid < 512)
                    *(f4*)&S[rbi*768 + 512 + rk4] =
                        cload4(&rIn[(size_t)(b0+rbi)*NR*NW + rk4]);
                __syncthreads();
                if (act) {
                    #pragma unroll
                    for (int bi = 0; bi < 8; ++bi) {
                        const f4* B4 = (const f4*)(S + bi*768);
                        float a = dot4(o0,B4[l]) + dot4(o1,B4[l+64]) + dot4(o2,B4[128+l]);
                        a = wave_red(a);
                        if (l == 0) out[((size_t)(b0+bi)*NT + t)*NH + row] = a + bias;
                    }
                }
                __syncthreads();
            }
            flag_set(&FLG[F_O + og*16], (unsigned)(t+1), tid);
        }
    }
}

extern "C" void kernel_launch(void* const* d_in, const int* in_sizes, int n_in,
                              void* d_out, int out_size, void* d_ws, size_t ws_size,
                              hipStream_t stream) {
    (void)in_sizes; (void)n_in; (void)out_size; (void)ws_size;
    const float* x    = (const float*)d_in[0];
    const float* W_ih = (const float*)d_in[1];
    const float* W_hh = (const float*)d_in[2];
    const float* b_ih = (const float*)d_in[3];
    const float* b_hh = (const float*)d_in[4];
    const float* W_xi = (const float*)d_in[5];
    const float* b_xi = (const float*)d_in[6];
    const float* W_o  = (const float*)d_in[7];
    const float* b_o  = (const float*)d_in[8];
    float* out = (float*)d_out;
    float* ws  = (float*)d_ws;

    dnc_zero<<<1, 1024, 0, stream>>>(ws);

    void* args[] = { (void*)&x, (void*)&W_ih, (void*)&W_hh, (void*)&b_ih,
                     (void*)&b_hh, (void*)&W_xi, (void*)&b_xi, (void*)&W_o,
                     (void*)&b_o, (void*)&out, (void*)&ws };
    hipLaunchCooperativeKernel((void*)dnc_pipe2, dim3(NBLK), dim3(TPB),
                               args, 0, stream);
}

// Round 2
// 4606.498 us; speedup vs baseline: 1.2036x; 1.0679x over previous
//
#include <hip/hip_runtime.h>
#include <math.h>

#define TPB 1024
#define NBLK 160
#define NBATCH 32
#define NT 64
#define NH 512
#define NM 128
#define NR 4
#define NW 64
#define NI 768          // controller input size (H + R*W)
#define NXI 471         // interface vector size
#define NG 2048         // gate rows
#define EPSF 1e-6f
#define MS 65           // mem row stride (+1 pad)

// roles: [0,32) state (LSTM+xi+DNC+out) | [32,160) gates(128)

typedef float f4 __attribute__((ext_vector_type(4)));

// ws layout (float offsets). pub* parity double-buffered.
#define WS_PUBH  0                                 // [2][32][512]
#define WS_PUBRV (WS_PUBH + 2*NBATCH*NH)           // [2][32][256]
#define WS_PUBG  (WS_PUBRV + 2*NBATCH*NR*NW)       // [2][32][2048]
#define WS_FLAGS (WS_PUBG + 2*NBATCH*NG)           // per-producer flag lines
// flag arrays (uint offsets inside flag region); each flag on its own 64B line
#define F_H 0        // 32 state blocks: h published (init=1, after h(t): t+2)
#define F_R 512      // 32 state blocks: rv published (same encoding)
#define F_G 1024     // 128 gates blocks: gates(t) -> t+1
#define F_TOTAL 3072

__device__ __forceinline__ float sigm(float x){ return 1.0f/(1.0f+expf(-x)); }
__device__ __forceinline__ float sftp(float x){ return fmaxf(x,0.0f)+log1pf(expf(-fabsf(x))); }
__device__ __forceinline__ float dot4(f4 a, f4 b){
    return a.x*b.x + a.y*b.y + a.z*b.z + a.w*b.w;
}
__device__ __forceinline__ float wave_red(float v){
    #pragma unroll
    for (int o = 32; o > 0; o >>= 1) v += __shfl_down(v, o);
    return v;
}

// ---- coherent (L1/L2-bypassing, device-visible) WIDE accessors: sc0 sc1 ----
// waitcnt lives INSIDE each asm statement => value is genuinely ready when the
// statement retires (no rule-18 hoist hazard). Outputs early-clobber.
__device__ __forceinline__ f4 cload4(const float* p){
    f4 v;
    asm volatile("global_load_dwordx4 %0, %1, off sc0 sc1\n\t"
                 "s_waitcnt vmcnt(0)"
                 : "=&v"(v) : "v"(p) : "memory");
    return v;
}
__device__ __forceinline__ void cload4x2(const float* p0, const float* p1,
                                         f4& a, f4& b){
    asm volatile("global_load_dwordx4 %0, %2, off sc0 sc1\n\t"
                 "global_load_dwordx4 %1, %3, off sc0 sc1\n\t"
                 "s_waitcnt vmcnt(0)"
                 : "=&v"(a), "=&v"(b) : "v"(p0), "v"(p1) : "memory");
}
__device__ __forceinline__ void cload1x4(const float* p0, const float* p1,
                                         const float* p2, const float* p3,
                                         float& a, float& b, float& c, float& d){
    asm volatile("global_load_dword %0, %4, off sc0 sc1\n\t"
                 "global_load_dword %1, %5, off sc0 sc1\n\t"
                 "global_load_dword %2, %6, off sc0 sc1\n\t"
                 "global_load_dword %3, %7, off sc0 sc1\n\t"
                 "s_waitcnt vmcnt(0)"
                 : "=&v"(a), "=&v"(b), "=&v"(c), "=&v"(d)
                 : "v"(p0), "v"(p1), "v"(p2), "v"(p3) : "memory");
}
__device__ __forceinline__ void cstore4(float* p, f4 v){
    asm volatile("global_store_dwordx4 %0, %1, off sc0 sc1"
                 :: "v"(p), "v"(v) : "memory");
}

// ---- per-producer flag protocol: parallel polls, no RMW contention ----
// s_sleep(8) ~512cy backoff: 4x less poll fabric traffic than s_sleep(2),
// adds <=0.2us latency per hop (step budget is tens of us).
__device__ __forceinline__ void multi_wait(const unsigned int* f, int n,
                                           unsigned int tgt, int tid){
    if (tid < n) {
        const unsigned int* p = f + tid*16;       // one 64B line per flag
        while (__hip_atomic_load(p, __ATOMIC_RELAXED,
                                 __HIP_MEMORY_SCOPE_AGENT) < tgt)
            __builtin_amdgcn_s_sleep(8);
    }
    __syncthreads();
}
__device__ __forceinline__ void flag_set(unsigned int* f, unsigned int v, int tid){
    // every wave drains its own (asm) stores, then barrier, then one release store
    asm volatile("s_waitcnt vmcnt(0)" ::: "memory");
    __syncthreads();
    if (tid == 0)
        __hip_atomic_store(f, v, __ATOMIC_RELEASE, __HIP_MEMORY_SCOPE_AGENT);
}

__global__ void dnc_zero(float* ws){
    unsigned int* z = (unsigned int*)(ws + WS_FLAGS);
    for (int e = threadIdx.x; e < F_TOTAL; e += blockDim.x) z[e] = 0u;
}

// ---- pooled LDS (floats) ----
#define O_MEM 0
#define O_H   8320
#define O_C   8832
#define O_RW  9344
#define O_WWO 9856
#define O_WWN 9984
#define O_USG 10112
#define O_PRC 10240
#define O_XI  10368     // 480
#define O_KEY 10848
#define O_WK  11104
#define O_ER  11168
#define O_WV  11232
#define O_RS  11296
#define O_FG  11300
#define O_MD  11304
#define O_NK  11316
#define O_SC  11320
#define O_NMO 11328
#define O_NMN 11456
#define O_WCW 11584
#define O_UU  11712
#define O_SU  11840
#define O_CUM 11968
#define O_RNK 12096
#define O_CCW 12224
#define O_FWD 12736
#define O_RV  13248
#define O_RED 13504
#define O_OS  13512     // 512: out-row staging
#define O_LK  14024     // 16384: link matrix IN LDS (was global ws)
#define S_SZ  30408     // ~122 KB; 1 block/CU so occupancy unaffected
// gates role: staging S[0..8191], acc at 8192..8703 (disjoint role, safe)
#define O_ACC 8192

__global__ __launch_bounds__(TPB) void dnc_pipe2(
    const float* __restrict__ x, const float* __restrict__ W_ih,
    const float* __restrict__ W_hh, const float* __restrict__ b_ih,
    const float* __restrict__ b_hh, const float* __restrict__ W_xi,
    const float* __restrict__ b_xi, const float* __restrict__ W_o,
    const float* __restrict__ b_o, float* __restrict__ out,
    float* __restrict__ ws)
{
    __shared__ __align__(16) float S[S_SZ];

    const int tid = threadIdx.x;
    const int wv  = tid >> 6;
    const int l   = tid & 63;
    const int bid = blockIdx.x;

    float* __restrict__ pubH  = ws + WS_PUBH;
    float* __restrict__ pubRV = ws + WS_PUBRV;
    float* __restrict__ pubG  = ws + WS_PUBG;
    unsigned int* __restrict__ FLG = (unsigned int*)(ws + WS_FLAGS);

    if (bid < NBATCH) {
        // ========================= STATE block =========================
        const int b = bid;
        float* lk = S+O_LK;
        float* mem = S+O_MEM;  float* hS = S+O_H;   float* cS = S+O_C;
        float* rwS = S+O_RW;   float* wwO = S+O_WWO; float* wwN = S+O_WWN;
        float* usg = S+O_USG;  float* prc = S+O_PRC; float* xiS = S+O_XI;
        float* keys = S+O_KEY; float* wkey = S+O_WK; float* ers = S+O_ER;
        float* wvec = S+O_WV;  float* rstr = S+O_RS; float* fgte = S+O_FG;
        float* modes = S+O_MD; float* nkey = S+O_NK; float* sc = S+O_SC;
        float* nmo = S+O_NMO;  float* nmn = S+O_NMN; float* wcw = S+O_WCW;
        float* uu = S+O_UU;    float* su = S+O_SU;   float* cum = S+O_CUM;
        int*   rnk = (int*)(S+O_RNK);
        float* ccw = S+O_CCW;  float* fwdT = S+O_FWD; float* rv = S+O_RV;
        float* red = S+O_RED;  float* oS = S+O_OS;

        for (int e = tid; e < NM*NM; e += TPB) lk[e] = 0.0f;
        for (int e = tid; e < NM*NW; e += TPB) mem[(e>>6)*MS + (e&63)] = EPSF;
        for (int e = tid; e < NH; e += TPB){ hS[e]=0.0f; cS[e]=0.0f; }
        for (int e = tid; e < NR*NM; e += TPB) rwS[e]=0.0f;
        for (int e = tid; e < NM; e += TPB){ wwO[e]=0.0f; usg[e]=0.0f; prc[e]=0.0f; }
        // publish h_{-1}=0, rv_{-1}=0 into parity 1 (gates step 0 reads parity 1)
        {
            f4 z4 = {0.0f, 0.0f, 0.0f, 0.0f};
            if (tid < 128) cstore4(&pubH[(size_t)1*NBATCH*NH + b*NH + tid*4], z4);
            if (tid < 64)  cstore4(&pubRV[(size_t)1*NBATCH*NR*NW + b*NR*NW + tid*4], z4);
        }
        flag_set(&FLG[F_H + b*16], 1u, tid);
        flag_set(&FLG[F_R + b*16], 1u, tid);

        for (int t = 0; t < NT; ++t) {
            const int par = t & 1;
            // gates(t) ready (all 128 producer flags, polled in parallel)
            multi_wait(&FLG[F_G], 128, (unsigned)(t+1), tid);
            {
                const float* gb = pubG + ((size_t)par*NBATCH + b)*NG;
                if (tid < NH) {
                    float vi, vf, vg, vo;
                    cload1x4(gb+tid, gb+NH+tid, gb+2*NH+tid, gb+3*NH+tid,
                             vi, vf, vg, vo);
                    float c = sigm(vf)*cS[tid] + sigm(vi)*tanhf(vg);
                    cS[tid] = c;
                    hS[tid] = sigm(vo)*tanhf(c);
                }
            }
            __syncthreads();
            if (tid < 128) cstore4(&pubH[(size_t)par*NBATCH*NH + b*NH + tid*4],
                                   *(const f4*)&hS[tid*4]);
            flag_set(&FLG[F_H + b*16], (unsigned)(t+2), tid);

            // ---- xi(t) computed IN-STATE (no round trip): 30 rows/wave ----
            {
                const f4* H4 = (const f4*)hS;
                const int r0 = wv*30;
                #pragma unroll 3
                for (int i = 0; i < 30; ++i) {
                    const int row = r0 + i;
                    if (row < NXI) {          // wave-uniform guard
                        const f4* WX = (const f4*)(W_xi + (size_t)row*NH);
                        float a = dot4(WX[l], H4[l]) + dot4(WX[l+64], H4[l+64]);
                        a = wave_red(a);
                        if (l == 0) xiS[row] = a + b_xi[row];
                    }
                }
            }
            // nmo — old mem norms (mem stable since last step's write)
            #pragma unroll
            for (int ri = 0; ri < 8; ++ri) {
                int row = wv*8 + ri;
                float v = mem[row*MS + l];
                float s2 = wave_red(v*v);
                if (l == 0) nmo[row] = sqrtf(s2);
            }
            __syncthreads();

            // E1: unpack interface
            if (tid < 256)       keys[tid] = tanhf(xiS[tid]);
            else if (tid < 260)  rstr[tid-256] = sftp(xiS[tid]);
            else if (tid < 324)  wkey[tid-260] = tanhf(xiS[tid]);
            else if (tid == 324) sc[0] = sftp(xiS[324]);
            else if (tid < 389)  ers[tid-325] = sigm(xiS[tid]);
            else if (tid < 453)  wvec[tid-389] = tanhf(xiS[tid]);
            else if (tid < 457)  fgte[tid-453] = sigm(xiS[tid]);
            else if (tid == 457) sc[1] = sigm(xiS[457]);
            else if (tid == 458) sc[2] = sigm(xiS[458]);
            else if (tid < 463) {
                int r = tid - 459;
                float a0=xiS[459+3*r], a1=xiS[460+3*r], a2=xiS[461+3*r];
                float mx = fmaxf(a0, fmaxf(a1, a2));
                float e0=expf(a0-mx), e1=expf(a1-mx), e2=expf(a2-mx);
                float si = 1.0f/(e0+e1+e2);
                modes[3*r]=e0*si; modes[3*r+1]=e1*si; modes[3*r+2]=e2*si;
            }
            __syncthreads();

            // E2a: key norms
            if (tid < NR) {
                float ssum = 0.0f;
                for (int w = 0; w < NW; ++w) { float v = keys[tid*NW+w]; ssum += v*v; }
                nkey[tid] = sqrtf(ssum);
            } else if (tid == NR) {
                float ssum = 0.0f;
                for (int w = 0; w < NW; ++w) { float v = wkey[w]; ssum += v*v; }
                sc[3] = sqrtf(ssum);
            }
            // E2b: usage + uu (fused)
            if (tid >= 64 && tid < 64+NM) {
                int m = tid - 64;
                float u = usg[m];
                u = u + (1.0f - u)*wwO[m];
                float psi = 1.0f;
                #pragma unroll
                for (int r = 0; r < NR; ++r) psi *= (1.0f - fgte[r]*rwS[r*NM+m]);
                u *= psi;
                usg[m] = u;
                uu[m] = 5e-6f + (1.0f - 5e-6f)*u;
            }
            __syncthreads();

            // F1: write-content logits
            if (tid < NM) {
                float d = 0.0f;
                for (int w = 0; w < NW; ++w) d += wkey[w]*mem[tid*MS+w];
                wcw[tid] = d/(sc[3]*nmo[tid] + EPSF) * sc[0];
            }
            __syncthreads();
            // F2: softmax over 128
            if (tid < 64) {
                float v = fmaxf(wcw[tid], wcw[tid+64]);
                #pragma unroll
                for (int o = 32; o > 0; o >>= 1) v = fmaxf(v, __shfl_down(v, o));
                if (tid == 0) red[0] = v;
            }
            __syncthreads();
            if (tid < NM) wcw[tid] = expf(wcw[tid] - red[0]);
            __syncthreads();
            if (tid < 64) {
                float v = wave_red(wcw[tid] + wcw[tid+64]);
                if (tid == 0) red[0] = 1.0f/v;
            }
            __syncthreads();
            if (tid < NM) wcw[tid] *= red[0];
            __syncthreads();

            // G2: stable rank
            if (tid < NM) {
                float um = uu[tid]; int rk = 0;
                for (int j = 0; j < NM; ++j) {
                    float uj = uu[j];
                    rk += (uj < um) || (uj == um && j < tid);
                }
                rnk[tid] = rk;
                su[rk] = um;
            }
            __syncthreads();
            // G3: product scan (wave 0)
            if (tid < 64) {
                float a = su[tid], bb = su[64+tid];
                #pragma unroll
                for (int o = 1; o < 64; o <<= 1) {
                    float ta = __shfl_up(a, o);
                    float tb = __shfl_up(bb, o);
                    if (tid >= o) { a *= ta; bb *= tb; }
                }
                float P0 = __shfl(a, 63);
                cum[tid] = a;
                cum[64+tid] = P0*bb;
            }
            __syncthreads();
            // G4: alloc + write weighting
            if (tid < NM) {
                int rk = rnk[tid];
                float excl = (rk == 0) ? 1.0f : cum[rk-1];
                float al = (1.0f - uu[tid])*excl;
                wwN[tid] = sc[2]*(sc[1]*al + (1.0f - sc[1])*wcw[tid]);
            }
            __syncthreads();
            // G5: sum(wwN)
            if (tid < 64) {
                float v = wave_red(wwN[tid] + wwN[tid+64]);
                if (tid == 0) sc[4] = v;
            }
            __syncthreads();

            // H (fused): mem erase/write + new norms + link (lk now in LDS)
            #pragma unroll
            for (int ri = 0; ri < 8; ++ri) {
                int row = wv*8 + ri;
                float wm = wwN[row];
                float v = mem[row*MS + l];
                float nv = v*(1.0f - wm*ers[l]) + wm*wvec[l];
                mem[row*MS + l] = nv;
                float s2 = wave_red(nv*nv);
                if (l == 0) nmn[row] = sqrtf(s2);
            }
            for (int e = tid; e < NM*NM; e += TPB) {
                int i = e >> 7, j = e & 127;
                float nl = (i == j) ? 0.0f
                         : (1.0f - wwN[i] - wwN[j])*lk[e] + wwN[i]*prc[j];
                lk[e] = nl;
            }
            __syncthreads();
            // H3: precedence
            if (tid < NM) prc[tid] = (1.0f - sc[4])*prc[tid] + wwN[tid];
            __syncthreads();

            // I: read-content logits + per-r softmax
            if (tid < NR*NM) {
                int r = tid >> 7, m = tid & 127;
                float d = 0.0f;
                for (int w = 0; w < NW; ++w) d += keys[r*NW+w]*mem[m*MS+w];
                ccw[tid] = d/(nkey[r]*nmn[m] + EPSF) * rstr[r];
            }
            __syncthreads();
            if (tid < 256) {
                int r = tid >> 6, ll = tid & 63;
                float v = fmaxf(ccw[r*NM+ll], ccw[r*NM+ll+64]);
                #pragma unroll
                for (int o = 32; o > 0; o >>= 1) v = fmaxf(v, __shfl_down(v, o));
                if (ll == 0) red[r] = v;
            }
            __syncthreads();
            if (tid < NR*NM) ccw[tid] = expf(ccw[tid] - red[tid>>7]);
            __syncthreads();
            if (tid < 256) {
                int r = tid >> 6, ll = tid & 63;
                float v = wave_red(ccw[r*NM+ll] + ccw[r*NM+ll+64]);
                if (ll == 0) red[4+r] = 1.0f/v;
            }
            __syncthreads();
            if (tid < NR*NM) ccw[tid] *= red[4+(tid>>7)];
            __syncthreads();

            // J1: fwd[r][m]
            {
                const int p0 = wv*32;
                for (int i = 0; i < 32; ++i) {
                    const int p = p0 + i, r = p >> 7, m = p & 127;
                    float partial = lk[m*NM + l]*rwS[r*NM + l]
                                  + lk[m*NM + 64 + l]*rwS[r*NM + 64 + l];
                    partial = wave_red(partial);
                    if (l == 0) fwdT[p] = partial;
                }
            }
            __syncthreads();
            // J2: bwd + mode mix
            float rwnew = 0.0f;
            if (tid < NR*NM) {
                int r = tid >> 7, m = tid & 127;
                float bw = 0.0f;
                for (int i = 0; i < NM; ++i) bw += lk[i*NM+m]*rwS[r*NM+i];
                rwnew = modes[3*r]*bw + modes[3*r+1]*fwdT[tid] + modes[3*r+2]*ccw[tid];
            }
            __syncthreads();
            if (tid < NR*NM) rwS[tid] = rwnew;
            __syncthreads();

            // K: read vectors + publish rv (coalesced f4)
            if (tid < NR*NW) {
                int r = tid >> 6, w = tid & 63;
                float ssum = 0.0f;
                for (int m = 0; m < NM; ++m) ssum += rwS[r*NM+m]*mem[m*MS+w];
                rv[tid] = ssum;
            }
            __syncthreads();
            if (tid < 64)
                cstore4(&pubRV[(size_t)par*NBATCH*NR*NW + b*NR*NW + tid*4],
                        *(const f4*)&rv[tid*4]);
            flag_set(&FLG[F_R + b*16], (unsigned)(t+2), tid);

            if (tid < NM) wwO[tid] = wwN[tid];

            // ---- out(t) IN-STATE, in the slack while gates produce t+1 ----
            {
                const f4* H4 = (const f4*)hS;
                const f4* RV4 = (const f4*)rv;
                const int r0 = wv*32;
                #pragma unroll 4
                for (int i = 0; i < 32; ++i) {
                    const int row = r0 + i;
                    const f4* WO = (const f4*)(W_o + (size_t)row*NI);
                    float a = dot4(WO[l], H4[l]) + dot4(WO[l+64], H4[l+64])
                            + dot4(WO[128+l], RV4[l]);
                    a = wave_red(a);
                    if (l == 0) oS[row] = a + b_o[row];
                }
            }
            __syncthreads();
            if (tid < 128)
                *(f4*)&out[((size_t)b*NT + t)*NH + tid*4] = *(const f4*)&oS[tid*4];
            __syncthreads();
        }
    } else {
        // ========================= GATES block (16 rows) ====================
        const int g = bid - 32;
        const int r = g*16 + wv;
        const f4* WA = (const f4*)(W_ih + (size_t)r*NI);
        f4 wx0 = WA[l], wx1 = WA[l+64], wrv = WA[128+l];
        const f4* WB = (const f4*)(W_hh + (size_t)r*NH);
        f4 wh0 = WB[l], wh1 = WB[l+64];
        const float bias = b_ih[r] + b_hh[r];
        float* accS = S + O_ACC;   // [32 batches][16 rows] transpose staging
        const int sbi = tid >> 7, sk4 = (tid & 127) << 2;

        for (int t = 0; t < NT; ++t) {
            const int par = t & 1, parp = (t+1) & 1;   // parp = parity of t-1
            // EARLY: x(t) + h(t-1) — overlaps state machinery of step t-1
            multi_wait(&FLG[F_H], 32, (unsigned)(t+1), tid);
            const float* hIn = pubH + (size_t)parp*NBATCH*NH;
            for (int p = 0; p < 4; ++p) {
                const int b0 = p*8;
                // x: 8 batches x 512 (plain cached f4), h: coherent f4
                *(f4*)&S[sbi*512 + sk4] =
                    *(const f4*)&x[((size_t)(b0+sbi)*NT + t)*NH + sk4];
                *(f4*)&S[4096 + sbi*512 + sk4] =
                    cload4(&hIn[(size_t)(b0+sbi)*NH + sk4]);
                __syncthreads();
                #pragma unroll
                for (int bi = 0; bi < 8; ++bi) {
                    const f4* X4 = (const f4*)(S + bi*512);
                    const f4* H4 = (const f4*)(S + 4096 + bi*512);
                    float a = dot4(wx0, X4[l]) + dot4(wx1, X4[l+64])
                            + dot4(wh0, H4[l]) + dot4(wh1, H4[l+64]);
                    a = wave_red(a);
                    if (l == 0) accS[(b0+bi)*16 + wv] = a + bias;
                }
                __syncthreads();
            }
            // LATE: rv(t-1) — the only critical-path part
            multi_wait(&FLG[F_R], 32, (unsigned)(t+1), tid);
            const float* rIn = pubRV + (size_t)parp*NBATCH*NR*NW;
            {
                const int bi0 = tid >> 6, k40 = (tid & 63) << 2;
                f4 a0, a1;
                cload4x2(&rIn[bi0*256 + k40], &rIn[(bi0+16)*256 + k40], a0, a1);
                *(f4*)&S[bi0*256 + k40] = a0;
                *(f4*)&S[(bi0+16)*256 + k40] = a1;
            }
            __syncthreads();
            #pragma unroll
            for (int bi = 0; bi < 32; ++bi) {
                const f4* RV4 = (const f4*)(S + bi*256);
                float d = dot4(wrv, RV4[l]);
                d = wave_red(d);
                if (l == 0) accS[bi*16 + wv] += d;
            }
            __syncthreads();
            // coalesced publish: 16 rows x 4B = one aligned 64B line per batch
            float* gOut = pubG + (size_t)par*NBATCH*NG;
            if (tid < 128) {
                const int bi = tid >> 2, r4 = (tid & 3) << 2;
                cstore4(&gOut[(size_t)bi*NG + g*16 + r4],
                        *(const f4*)&accS[bi*16 + r4]);
            }
            flag_set(&FLG[F_G + g*16], (unsigned)(t+1), tid);
        }
    }
}

extern "C" void kernel_launch(void* const* d_in, const int* in_sizes, int n_in,
                              void* d_out, int out_size, void* d_ws, size_t ws_size,
                              hipStream_t stream) {
    (void)in_sizes; (void)n_in; (void)out_size; (void)ws_size;
    const float* x    = (const float*)d_in[0];
    const float* W_ih = (const float*)d_in[1];
    const float* W_hh = (const float*)d_in[2];
    const float* b_ih = (const float*)d_in[3];
    const float* b_hh = (const float*)d_in[4];
    const float* W_xi = (const float*)d_in[5];
    const float* b_xi = (const float*)d_in[6];
    const float* W_o  = (const float*)d_in[7];
    const float* b_o  = (const float*)d_in[8];
    float* out = (float*)d_out;
    float* ws  = (float*)d_ws;

    dnc_zero<<<1, 1024, 0, stream>>>(ws);

    void* args[] = { (void*)&x, (void*)&W_ih, (void*)&W_hh, (void*)&b_ih,
                     (void*)&b_hh, (void*)&W_xi, (void*)&b_xi, (void*)&W_o,
                     (void*)&b_o, (void*)&out, (void*)&ws };
    hipLaunchCooperativeKernel((void*)dnc_pipe2, dim3(NBLK), dim3(TPB),
                               args, 0, stream);
}

// Round 3
// 4517.122 us; speedup vs baseline: 1.2274x; 1.0198x over previous
//
#include <hip/hip_runtime.h>
#include <math.h>

#define TPB 1024
#define NBLK 160
#define NBATCH 32
#define NT 64
#define NH 512
#define NM 128
#define NR 4
#define NW 64
#define NI 768          // controller input size (H + R*W)
#define NXI 471         // interface vector size
#define EPSF 1e-6f
#define MS 65           // mem row stride (+1 pad)

// roles: [0,32) state (xi+DNC+out) | [32,160) gates blocks (16 rows = 4 units x 4 gates, +LSTM cell)

typedef float f4 __attribute__((ext_vector_type(4)));

// ws layout (float offsets). pub* parity double-buffered.
#define WS_PUBH  0                                 // [2][32][512] (written by gates!)
#define WS_PUBRV (WS_PUBH + 2*NBATCH*NH)           // [2][32][256]
#define WS_FLAGS (WS_PUBRV + 2*NBATCH*NR*NW)
// packed flag dwords: 16 flags per 64B line (parallel coalesced polls)
#define D_G 0        // 128 gate blocks: h(t) published -> t+1
#define D_R 128      // 32 state blocks: rv(t) published -> t+1
#define D_TOTAL 160

__device__ __forceinline__ float sigm(float x){ return 1.0f/(1.0f+expf(-x)); }
__device__ __forceinline__ float sftp(float x){ return fmaxf(x,0.0f)+log1pf(expf(-fabsf(x))); }
__device__ __forceinline__ float dot4(f4 a, f4 b){
    return a.x*b.x + a.y*b.y + a.z*b.z + a.w*b.w;
}
__device__ __forceinline__ float wave_red(float v){
    #pragma unroll
    for (int o = 32; o > 0; o >>= 1) v += __shfl_down(v, o);
    return v;
}

// ---- coherent (LLC write-through, device-visible) accessors: sc0 sc1 ----
// waitcnt INSIDE each asm statement => no rule-18 hoist hazard.
__device__ __forceinline__ f4 cload4(const float* p){
    f4 v;
    asm volatile("global_load_dwordx4 %0, %1, off sc0 sc1\n\t"
                 "s_waitcnt vmcnt(0)"
                 : "=&v"(v) : "v"(p) : "memory");
    return v;
}
__device__ __forceinline__ void cload4x2(const float* p0, const float* p1,
                                         f4& a, f4& b){
    asm volatile("global_load_dwordx4 %0, %2, off sc0 sc1\n\t"
                 "global_load_dwordx4 %1, %3, off sc0 sc1\n\t"
                 "s_waitcnt vmcnt(0)"
                 : "=&v"(a), "=&v"(b) : "v"(p0), "v"(p1) : "memory");
}
__device__ __forceinline__ void cload4x4(const float* p0, const float* p1,
                                         const float* p2, const float* p3,
                                         f4& a, f4& b, f4& c, f4& d){
    asm volatile("global_load_dwordx4 %0, %4, off sc0 sc1\n\t"
                 "global_load_dwordx4 %1, %5, off sc0 sc1\n\t"
                 "global_load_dwordx4 %2, %6, off sc0 sc1\n\t"
                 "global_load_dwordx4 %3, %7, off sc0 sc1\n\t"
                 "s_waitcnt vmcnt(0)"
                 : "=&v"(a), "=&v"(b), "=&v"(c), "=&v"(d)
                 : "v"(p0), "v"(p1), "v"(p2), "v"(p3) : "memory");
}
__device__ __forceinline__ void cstore4(float* p, f4 v){
    asm volatile("global_store_dwordx4 %0, %1, off sc0 sc1"
                 :: "v"(p), "v"(v) : "memory");
}

// ---- packed-flag protocol: coalesced parallel polls, no RMW, no RELEASE ----
__device__ __forceinline__ void multi_wait_d(const unsigned int* f, int n,
                                             unsigned int tgt, int tid){
    if (tid < n) {
        const unsigned int* p = f + tid;          // consecutive dwords: coalesced
        while (__hip_atomic_load(p, __ATOMIC_RELAXED,
                                 __HIP_MEMORY_SCOPE_AGENT) < tgt)
            __builtin_amdgcn_s_sleep(2);
    }
    __syncthreads();
}
// data stores are all sc0 sc1 (write-through to coherence point); vmcnt(0)
// drain per wave + barrier + RELAXED flag store is a correct release without
// the compiler's agent-release L2-writeback.
__device__ __forceinline__ void flag_set_d(unsigned int* f, unsigned int v, int tid){
    asm volatile("s_waitcnt vmcnt(0)" ::: "memory");
    __syncthreads();
    if (tid == 0)
        __hip_atomic_store(f, v, __ATOMIC_RELAXED, __HIP_MEMORY_SCOPE_AGENT);
}

__global__ void dnc_zero(float* ws){
    unsigned int* z = (unsigned int*)(ws + WS_FLAGS);
    for (int e = threadIdx.x; e < D_TOTAL; e += blockDim.x) z[e] = 0u;
}

// ---- pooled LDS (floats) ----
#define O_MEM 0
#define O_H   8320
#define O_RW  9344
#define O_WWO 9856
#define O_WWN 9984
#define O_USG 10112
#define O_PRC 10240
#define O_XI  10368     // 480
#define O_KEY 10848
#define O_WK  11104
#define O_ER  11168
#define O_WV  11232
#define O_RS  11296
#define O_FG  11300
#define O_MD  11304
#define O_NK  11316
#define O_SC  11320
#define O_NMO 11328
#define O_NMN 11456
#define O_WCW 11584
#define O_UU  11712
#define O_SU  11840
#define O_CUM 11968
#define O_RNK 12096
#define O_CCW 12224
#define O_FWD 12736
#define O_RV  13248
#define O_RED 13504
#define O_OS  13512     // 512: out-row staging
#define O_LK  14024     // 16384: link matrix in LDS
#define S_SZ  30408     // ~119 KB; 1 block/CU
// gates role (disjoint): x/rv staging S[0..8191], acc 8192, c 8704, h-stage 8832
#define G_ACC 8192
#define G_C   8704
#define G_H   8832      // 16384 floats: all 32 batches' h(t-1)

__global__ __launch_bounds__(TPB) void dnc_pipe2(
    const float* __restrict__ x, const float* __restrict__ W_ih,
    const float* __restrict__ W_hh, const float* __restrict__ b_ih,
    const float* __restrict__ b_hh, const float* __restrict__ W_xi,
    const float* __restrict__ b_xi, const float* __restrict__ W_o,
    const float* __restrict__ b_o, float* __restrict__ out,
    float* __restrict__ ws)
{
    __shared__ __align__(16) float S[S_SZ];

    const int tid = threadIdx.x;
    const int wv  = tid >> 6;
    const int l   = tid & 63;
    const int bid = blockIdx.x;

    float* __restrict__ pubH  = ws + WS_PUBH;
    float* __restrict__ pubRV = ws + WS_PUBRV;
    unsigned int* __restrict__ FLGD = (unsigned int*)(ws + WS_FLAGS);

    if (bid < NBATCH) {
        // ========================= STATE block =========================
        const int b = bid;
        float* lk = S+O_LK;
        float* mem = S+O_MEM;  float* hS = S+O_H;
        float* rwS = S+O_RW;   float* wwO = S+O_WWO; float* wwN = S+O_WWN;
        float* usg = S+O_USG;  float* prc = S+O_PRC; float* xiS = S+O_XI;
        float* keys = S+O_KEY; float* wkey = S+O_WK; float* ers = S+O_ER;
        float* wvec = S+O_WV;  float* rstr = S+O_RS; float* fgte = S+O_FG;
        float* modes = S+O_MD; float* nkey = S+O_NK; float* sc = S+O_SC;
        float* nmo = S+O_NMO;  float* nmn = S+O_NMN; float* wcw = S+O_WCW;
        float* uu = S+O_UU;    float* su = S+O_SU;   float* cum = S+O_CUM;
        int*   rnk = (int*)(S+O_RNK);
        float* ccw = S+O_CCW;  float* fwdT = S+O_FWD; float* rv = S+O_RV;
        float* red = S+O_RED;  float* oS = S+O_OS;

        for (int e = tid; e < NM*NM; e += TPB) lk[e] = 0.0f;
        for (int e = tid; e < NM*NW; e += TPB) mem[(e>>6)*MS + (e&63)] = EPSF;
        for (int e = tid; e < NR*NM; e += TPB) rwS[e]=0.0f;
        for (int e = tid; e < NM; e += TPB){ wwO[e]=0.0f; usg[e]=0.0f; prc[e]=0.0f; }
        __syncthreads();

        for (int t = 0; t < NT; ++t) {
            const int par = t & 1;
            // h(t) ready from all 128 gate blocks (packed-dword poll)
            multi_wait_d(&FLGD[D_G], 128, (unsigned)(t+1), tid);
            // overlap: waves 0-1 fetch h while all waves do old-mem norms
            if (tid < 128)
                *(f4*)&hS[tid*4] =
                    cload4(&pubH[(size_t)par*NBATCH*NH + b*NH + tid*4]);
            #pragma unroll
            for (int ri = 0; ri < 8; ++ri) {
                int row = wv*8 + ri;
                float v = mem[row*MS + l];
                float s2 = wave_red(v*v);
                if (l == 0) nmo[row] = sqrtf(s2);
            }
            __syncthreads();

            // ---- xi(t) in-state: 30 rows/wave ----
            {
                const f4* H4 = (const f4*)hS;
                const int r0 = wv*30;
                #pragma unroll 3
                for (int i = 0; i < 30; ++i) {
                    const int row = r0 + i;
                    if (row < NXI) {          // wave-uniform guard
                        const f4* WX = (const f4*)(W_xi + (size_t)row*NH);
                        float a = dot4(WX[l], H4[l]) + dot4(WX[l+64], H4[l+64]);
                        a = wave_red(a);
                        if (l == 0) xiS[row] = a + b_xi[row];
                    }
                }
            }
            __syncthreads();

            // E1: unpack interface
            if (tid < 256)       keys[tid] = tanhf(xiS[tid]);
            else if (tid < 260)  rstr[tid-256] = sftp(xiS[tid]);
            else if (tid < 324)  wkey[tid-260] = tanhf(xiS[tid]);
            else if (tid == 324) sc[0] = sftp(xiS[324]);
            else if (tid < 389)  ers[tid-325] = sigm(xiS[tid]);
            else if (tid < 453)  wvec[tid-389] = tanhf(xiS[tid]);
            else if (tid < 457)  fgte[tid-453] = sigm(xiS[tid]);
            else if (tid == 457) sc[1] = sigm(xiS[457]);
            else if (tid == 458) sc[2] = sigm(xiS[458]);
            else if (tid < 463) {
                int r = tid - 459;
                float a0=xiS[459+3*r], a1=xiS[460+3*r], a2=xiS[461+3*r];
                float mx = fmaxf(a0, fmaxf(a1, a2));
                float e0=expf(a0-mx), e1=expf(a1-mx), e2=expf(a2-mx);
                float si = 1.0f/(e0+e1+e2);
                modes[3*r]=e0*si; modes[3*r+1]=e1*si; modes[3*r+2]=e2*si;
            }
            __syncthreads();

            // E2a: key norms
            if (tid < NR) {
                float ssum = 0.0f;
                for (int w = 0; w < NW; ++w) { float v = keys[tid*NW+w]; ssum += v*v; }
                nkey[tid] = sqrtf(ssum);
            } else if (tid == NR) {
                float ssum = 0.0f;
                for (int w = 0; w < NW; ++w) { float v = wkey[w]; ssum += v*v; }
                sc[3] = sqrtf(ssum);
            }
            // E2b: usage + uu (fused)
            if (tid >= 64 && tid < 64+NM) {
                int m = tid - 64;
                float u = usg[m];
                u = u + (1.0f - u)*wwO[m];
                float psi = 1.0f;
                #pragma unroll
                for (int r = 0; r < NR; ++r) psi *= (1.0f - fgte[r]*rwS[r*NM+m]);
                u *= psi;
                usg[m] = u;
                uu[m] = 5e-6f + (1.0f - 5e-6f)*u;
            }
            __syncthreads();

            // F1: write-content logits
            if (tid < NM) {
                float d = 0.0f;
                for (int w = 0; w < NW; ++w) d += wkey[w]*mem[tid*MS+w];
                wcw[tid] = d/(sc[3]*nmo[tid] + EPSF) * sc[0];
            }
            __syncthreads();
            // F2: softmax over 128
            if (tid < 64) {
                float v = fmaxf(wcw[tid], wcw[tid+64]);
                #pragma unroll
                for (int o = 32; o > 0; o >>= 1) v = fmaxf(v, __shfl_down(v, o));
                if (tid == 0) red[0] = v;
            }
            __syncthreads();
            if (tid < NM) wcw[tid] = expf(wcw[tid] - red[0]);
            __syncthreads();
            if (tid < 64) {
                float v = wave_red(wcw[tid] + wcw[tid+64]);
                if (tid == 0) red[0] = 1.0f/v;
            }
            __syncthreads();
            if (tid < NM) wcw[tid] *= red[0];
            __syncthreads();

            // G2: stable rank
            if (tid < NM) {
                float um = uu[tid]; int rk = 0;
                for (int j = 0; j < NM; ++j) {
                    float uj = uu[j];
                    rk += (uj < um) || (uj == um && j < tid);
                }
                rnk[tid] = rk;
                su[rk] = um;
            }
            __syncthreads();
            // G3: product scan (wave 0)
            if (tid < 64) {
                float a = su[tid], bb = su[64+tid];
                #pragma unroll
                for (int o = 1; o < 64; o <<= 1) {
                    float ta = __shfl_up(a, o);
                    float tb = __shfl_up(bb, o);
                    if (tid >= o) { a *= ta; bb *= tb; }
                }
                float P0 = __shfl(a, 63);
                cum[tid] = a;
                cum[64+tid] = P0*bb;
            }
            __syncthreads();
            // G4: alloc + write weighting
            if (tid < NM) {
                int rk = rnk[tid];
                float excl = (rk == 0) ? 1.0f : cum[rk-1];
                float al = (1.0f - uu[tid])*excl;
                wwN[tid] = sc[2]*(sc[1]*al + (1.0f - sc[1])*wcw[tid]);
            }
            __syncthreads();
            // G5: sum(wwN)
            if (tid < 64) {
                float v = wave_red(wwN[tid] + wwN[tid+64]);
                if (tid == 0) sc[4] = v;
            }
            __syncthreads();

            // H (fused): mem erase/write + new norms + link
            #pragma unroll
            for (int ri = 0; ri < 8; ++ri) {
                int row = wv*8 + ri;
                float wm = wwN[row];
                float v = mem[row*MS + l];
                float nv = v*(1.0f - wm*ers[l]) + wm*wvec[l];
                mem[row*MS + l] = nv;
                float s2 = wave_red(nv*nv);
                if (l == 0) nmn[row] = sqrtf(s2);
            }
            for (int e = tid; e < NM*NM; e += TPB) {
                int i = e >> 7, j = e & 127;
                float nl = (i == j) ? 0.0f
                         : (1.0f - wwN[i] - wwN[j])*lk[e] + wwN[i]*prc[j];
                lk[e] = nl;
            }
            __syncthreads();
            // H3: precedence
            if (tid < NM) prc[tid] = (1.0f - sc[4])*prc[tid] + wwN[tid];
            __syncthreads();

            // I: read-content logits + per-r softmax
            if (tid < NR*NM) {
                int r = tid >> 7, m = tid & 127;
                float d = 0.0f;
                for (int w = 0; w < NW; ++w) d += keys[r*NW+w]*mem[m*MS+w];
                ccw[tid] = d/(nkey[r]*nmn[m] + EPSF) * rstr[r];
            }
            __syncthreads();
            if (tid < 256) {
                int r = tid >> 6, ll = tid & 63;
                float v = fmaxf(ccw[r*NM+ll], ccw[r*NM+ll+64]);
                #pragma unroll
                for (int o = 32; o > 0; o >>= 1) v = fmaxf(v, __shfl_down(v, o));
                if (ll == 0) red[r] = v;
            }
            __syncthreads();
            if (tid < NR*NM) ccw[tid] = expf(ccw[tid] - red[tid>>7]);
            __syncthreads();
            if (tid < 256) {
                int r = tid >> 6, ll = tid & 63;
                float v = wave_red(ccw[r*NM+ll] + ccw[r*NM+ll+64]);
                if (ll == 0) red[4+r] = 1.0f/v;
            }
            __syncthreads();
            if (tid < NR*NM) ccw[tid] *= red[4+(tid>>7)];
            __syncthreads();

            // J1: fwd[r][m]
            {
                const int p0 = wv*32;
                for (int i = 0; i < 32; ++i) {
                    const int p = p0 + i, r = p >> 7, m = p & 127;
                    float partial = lk[m*NM + l]*rwS[r*NM + l]
                                  + lk[m*NM + 64 + l]*rwS[r*NM + 64 + l];
                    partial = wave_red(partial);
                    if (l == 0) fwdT[p] = partial;
                }
            }
            __syncthreads();
            // J2: bwd + mode mix
            float rwnew = 0.0f;
            if (tid < NR*NM) {
                int r = tid >> 7, m = tid & 127;
                float bw = 0.0f;
                for (int i = 0; i < NM; ++i) bw += lk[i*NM+m]*rwS[r*NM+i];
                rwnew = modes[3*r]*bw + modes[3*r+1]*fwdT[tid] + modes[3*r+2]*ccw[tid];
            }
            __syncthreads();
            if (tid < NR*NM) rwS[tid] = rwnew;
            __syncthreads();

            // K: read vectors + publish rv
            if (tid < NR*NW) {
                int r = tid >> 6, w = tid & 63;
                float ssum = 0.0f;
                for (int m = 0; m < NM; ++m) ssum += rwS[r*NM+m]*mem[m*MS+w];
                rv[tid] = ssum;
            }
            __syncthreads();
            if (tid < 64)
                cstore4(&pubRV[(size_t)par*NBATCH*NR*NW + b*NR*NW + tid*4],
                        *(const f4*)&rv[tid*4]);
            flag_set_d(&FLGD[D_R + b], (unsigned)(t+1), tid);

            if (tid < NM) wwO[tid] = wwN[tid];

            // ---- out(t) in-state, in the slack while gates produce t+1 ----
            {
                const f4* H4 = (const f4*)hS;
                const f4* RV4 = (const f4*)rv;
                const int r0 = wv*32;
                #pragma unroll 4
                for (int i = 0; i < 32; ++i) {
                    const int row = r0 + i;
                    const f4* WO = (const f4*)(W_o + (size_t)row*NI);
                    float a = dot4(WO[l], H4[l]) + dot4(WO[l+64], H4[l+64])
                            + dot4(WO[128+l], RV4[l]);
                    a = wave_red(a);
                    if (l == 0) oS[row] = a + b_o[row];
                }
            }
            __syncthreads();
            if (tid < 128)
                *(f4*)&out[((size_t)b*NT + t)*NH + tid*4] = *(const f4*)&oS[tid*4];
            __syncthreads();
        }
    } else {
        // ================= GATES block (4 hidden units, 16 rows, +LSTM) =====
        const int g = bid - 32;            // owns units u = 4g .. 4g+3
        const int gate = wv >> 2, j = wv & 3;
        const int r = gate*NH + 4*g + j;   // weight row: gate q, unit 4g+j
        const f4* WA = (const f4*)(W_ih + (size_t)r*NI);
        f4 wx0 = WA[l], wx1 = WA[l+64], wrv = WA[128+l];
        const f4* WB = (const f4*)(W_hh + (size_t)r*NH);
        f4 wh0 = WB[l], wh1 = WB[l+64];
        const float bias = b_ih[r] + b_hh[r];
        float* accS = S + G_ACC;   // [32 batches][16 rows]
        float* cSg  = S + G_C;     // [32 batches][4 units] cell state
        float* hStg = S + G_H;     // [32 batches][512] h(t-1) staging
        const int sbi = tid >> 7, sk4 = (tid & 127) << 2;

        if (tid < 128) cSg[tid] = 0.0f;
        for (int e = tid; e < NBATCH*NH; e += TPB) hStg[e] = 0.0f;  // h(-1)=0
        __syncthreads();

        for (int t = 0; t < NT; ++t) {
            const int par = t & 1, parp = (t+1) & 1;   // parp = parity of t-1
            // EARLY: stage ALL h(t-1) in one 4-load batch (one LLC latency)
            if (t > 0) {
                multi_wait_d(&FLGD[D_G], 128, (unsigned)t, tid);   // h(t-1) all
                const float* hIn = pubH + (size_t)parp*NBATCH*NH;
                f4 a0, a1, a2, a3;
                cload4x4(hIn + tid*4, hIn + (tid+1024)*4,
                         hIn + (tid+2048)*4, hIn + (tid+3072)*4,
                         a0, a1, a2, a3);
                *(f4*)&hStg[tid*4]          = a0;
                *(f4*)&hStg[(tid+1024)*4]   = a1;
                *(f4*)&hStg[(tid+2048)*4]   = a2;
                *(f4*)&hStg[(tid+3072)*4]   = a3;
            }
            for (int p = 0; p < 4; ++p) {
                const int b0 = p*8;
                // x: 8 batches x 512 (plain cached f4)
                *(f4*)&S[sbi*512 + sk4] =
                    *(const f4*)&x[((size_t)(b0+sbi)*NT + t)*NH + sk4];
                __syncthreads();
                #pragma unroll
                for (int bi = 0; bi < 8; ++bi) {
                    const f4* X4 = (const f4*)(S + bi*512);
                    const f4* H4 = (const f4*)(hStg + (b0+bi)*512);
                    float a = dot4(wx0, X4[l]) + dot4(wx1, X4[l+64])
                            + dot4(wh0, H4[l]) + dot4(wh1, H4[l+64]);
                    a = wave_red(a);
                    if (l == 0) accS[(b0+bi)*16 + wv] = a + bias;
                }
                __syncthreads();
            }
            // LATE: rv(t-1) — the only critical-path part
            {
                const int bi0 = tid >> 6, k40 = (tid & 63) << 2;
                if (t > 0) {
                    multi_wait_d(&FLGD[D_R], 32, (unsigned)t, tid);
                    const float* rIn = pubRV + (size_t)parp*NBATCH*NR*NW;
                    f4 a0, a1;
                    cload4x2(&rIn[bi0*256 + k40], &rIn[(bi0+16)*256 + k40], a0, a1);
                    *(f4*)&S[bi0*256 + k40] = a0;
                    *(f4*)&S[(bi0+16)*256 + k40] = a1;
                } else {
                    f4 z = {0.0f, 0.0f, 0.0f, 0.0f};
                    *(f4*)&S[bi0*256 + k40] = z;
                    *(f4*)&S[(bi0+16)*256 + k40] = z;
                }
            }
            __syncthreads();
            #pragma unroll
            for (int bi = 0; bi < 32; ++bi) {
                const f4* RV4 = (const f4*)(S + bi*256);
                float d = dot4(wrv, RV4[l]);
                d = wave_red(d);
                if (l == 0) accS[bi*16 + wv] += d;
            }
            __syncthreads();
            // LSTM cell for this block's 4 units x 32 batches, publish h-chunk
            if (tid < 32) {
                const int bi = tid;
                const float* acc = accS + bi*16;
                f4 hq;
                #pragma unroll
                for (int jj = 0; jj < 4; ++jj) {
                    float i_ = sigm(acc[0*4 + jj]);
                    float f_ = sigm(acc[1*4 + jj]);
                    float g_ = tanhf(acc[2*4 + jj]);
                    float o_ = sigm(acc[3*4 + jj]);
                    float c  = f_*cSg[bi*4 + jj] + i_*g_;
                    cSg[bi*4 + jj] = c;
                    hq[jj] = o_*tanhf(c);
                }
                cstore4(&pubH[(size_t)par*NBATCH*NH + (size_t)bi*NH + 4*g], hq);
            }
            flag_set_d(&FLGD[D_G + g], (unsigned)(t+1), tid);
        }
    }
}

extern "C" void kernel_launch(void* const* d_in, const int* in_sizes, int n_in,
                              void* d_out, int out_size, void* d_ws, size_t ws_size,
                              hipStream_t stream) {
    (void)in_sizes; (void)n_in; (void)out_size; (void)ws_size;
    const float* x    = (const float*)d_in[0];
    const float* W_ih = (const float*)d_in[1];
    const float* W_hh = (const float*)d_in[2];
    const float* b_ih = (const float*)d_in[3];
    const float* b_hh = (const float*)d_in[4];
    const float* W_xi = (const float*)d_in[5];
    const float* b_xi = (const float*)d_in[6];
    const float* W_o  = (const float*)d_in[7];
    const float* b_o  = (const float*)d_in[8];
    float* out = (float*)d_out;
    float* ws  = (float*)d_ws;

    dnc_zero<<<1, 256, 0, stream>>>(ws);

    void* args[] = { (void*)&x, (void*)&W_ih, (void*)&W_hh, (void*)&b_ih,
                     (void*)&b_hh, (void*)&W_xi, (void*)&b_xi, (void*)&W_o,
                     (void*)&b_o, (void*)&out, (void*)&ws };
    hipLaunchCooperativeKernel((void*)dnc_pipe2, dim3(NBLK), dim3(TPB),
                               args, 0, stream);
}